// Round 8
// baseline (402.585 us; speedup 1.0000x reference)
//
#include <hip/hip_runtime.h>
#include <stdint.h>

#define SEQ 4096
#define INDIM 1024
#define NODEDIM 512
#define NH 8
#define HD 64
#define LSTR 72  // padded LDS row stride (ushorts): 144B -> 4-bank rotation per row

typedef __bf16 bf16x8 __attribute__((ext_vector_type(8)));
typedef float f32x4 __attribute__((ext_vector_type(4)));

#define GLOAD_LDS(gp, lp) \
    __builtin_amdgcn_global_load_lds( \
        (const __attribute__((address_space(1))) void*)(gp), \
        (__attribute__((address_space(3))) void*)(lp), 16, 0, 0)

__device__ __forceinline__ unsigned short f2bf(float f) {
    union { float f; uint32_t u; } v; v.f = f;
    uint32_t u = v.u;
    uint32_t r = (u + 0x7fffu + ((u >> 16) & 1u)) >> 16;  // RNE
    return (unsigned short)r;
}

__device__ __forceinline__ float fast_exp2(float x) {
    float r;
    asm volatile("v_exp_f32 %0, %1" : "=v"(r) : "v"(x));
    return r;
}

// ---------------------------------------------------------------- cvt fp32->bf16 (all tensors, one launch)
__global__ __launch_bounds__(256) void cvt_all(const float* __restrict__ emb,
                                               const float* __restrict__ Wq,
                                               const float* __restrict__ Wk,
                                               const float* __restrict__ Wv,
                                               const float* __restrict__ Wo,
                                               unsigned short* __restrict__ demb,
                                               unsigned short* __restrict__ dwqkv,
                                               unsigned short* __restrict__ dwo) {
    int b = blockIdx.x;
    const float* src;
    unsigned short* dst;
    int off;
    if (b < 4096)      { src = emb; dst = demb;            off = b; }
    else if (b < 4608) { src = Wq;  dst = dwqkv;           off = b - 4096; }
    else if (b < 5120) { src = Wk;  dst = dwqkv + 524288;  off = b - 4608; }
    else if (b < 5632) { src = Wv;  dst = dwqkv + 1048576; off = b - 5120; }
    else               { src = Wo;  dst = dwo;             off = b - 5632; }
    int i = (off * 256 + threadIdx.x) * 4;
    float4 v = *(const float4*)(src + i);
    ushort4 o;
    o.x = f2bf(v.x); o.y = f2bf(v.y); o.z = f2bf(v.z); o.w = f2bf(v.w);
    *(ushort4*)(dst + i) = o;
}

// ---------------------------------------------------------------- QKV GEMM (r5 form)
__global__ __launch_bounds__(256) void qkv_gemm(const unsigned short* __restrict__ A,
                                                const unsigned short* __restrict__ B,
                                                const float* __restrict__ bq,
                                                const float* __restrict__ bk,
                                                const float* __restrict__ bv,
                                                unsigned short* __restrict__ Qo,
                                                unsigned short* __restrict__ Ko,
                                                unsigned short* __restrict__ VTo) {
    __shared__ unsigned short As[128 * 32];
    __shared__ unsigned short Bs[128 * 32];
    __shared__ unsigned short Ts[128 * 40];  // V-transpose staging
    const int tid = threadIdx.x;
    const int lane = tid & 63, wave = tid >> 6;
    const int wm = wave >> 1, wn = wave & 1;
    const int quad = lane >> 4, l16 = lane & 15;
    const int m0 = blockIdx.x * 128;
    const int n0 = blockIdx.y * 128;

    const int srow = tid >> 2, sqq = tid & 3;

    f32x4 acc[4][4] = {};

    for (int k0 = 0; k0 < INDIM; k0 += 32) {
        __syncthreads();
        for (int i = 0; i < 2; ++i) {
            int row = srow + 64 * i;
            GLOAD_LDS(A + (size_t)(m0 + row) * INDIM + k0 + sqq * 8, &As[row * 32 + sqq * 8]);
            GLOAD_LDS(B + (size_t)(n0 + row) * INDIM + k0 + sqq * 8, &Bs[row * 32 + sqq * 8]);
        }
        __syncthreads();
        bf16x8 af[4], bf[4];
        for (int mi = 0; mi < 4; ++mi)
            af[mi] = *(const bf16x8*)&As[(wm * 64 + mi * 16 + l16) * 32 + quad * 8];
        for (int ni = 0; ni < 4; ++ni)
            bf[ni] = *(const bf16x8*)&Bs[(wn * 64 + ni * 16 + l16) * 32 + quad * 8];
        for (int mi = 0; mi < 4; ++mi)
            for (int ni = 0; ni < 4; ++ni)
                acc[mi][ni] = __builtin_amdgcn_mfma_f32_16x16x32_bf16(af[mi], bf[ni], acc[mi][ni], 0, 0, 0);
    }

    if (blockIdx.y < 8) {
        unsigned short* outp = (blockIdx.y < 4) ? Qo : Ko;
        const float* biasp = (blockIdx.y < 4) ? bq : bk;
        for (int mi = 0; mi < 4; ++mi)
            for (int ni = 0; ni < 4; ++ni)
                for (int r = 0; r < 4; ++r) {
                    int s = m0 + wm * 64 + mi * 16 + quad * 4 + r;
                    int n = n0 + wn * 64 + ni * 16 + l16;
                    int h = (n >> 6) & 7;
                    int dd = n & 63;
                    float v = acc[mi][ni][r] + biasp[n & 511];
                    outp[((size_t)h * SEQ + s) * HD + dd] = f2bf(v);
                }
    } else {
        for (int chunk = 0; chunk < 4; ++chunk) {
            const int cwm = chunk >> 1;
            const int milo = (chunk & 1) * 2;
            __syncthreads();
            if (wm == cwm) {
                for (int mi2 = 0; mi2 < 2; ++mi2) {
                    int mi = milo + mi2;
                    for (int ni = 0; ni < 4; ++ni) {
                        int ddf = wn * 64 + ni * 16 + l16;
                        float bias = bv[(n0 + ddf) & 511];
                        for (int r = 0; r < 4; ++r) {
                            int sl = mi2 * 16 + quad * 4 + r;
                            Ts[ddf * 40 + sl] = f2bf(acc[mi][ni][r] + bias);
                        }
                    }
                }
            }
            __syncthreads();
            for (int pass = 0; pass < 2; ++pass) {
                int c = pass * 256 + tid;
                int row = c >> 2, part = c & 3;
                int nfull = n0 + row;
                int h = (nfull >> 6) & 7, dd = nfull & 63;
                *(bf16x8*)(VTo + ((size_t)h * HD + dd) * SEQ + m0 + chunk * 32 + part * 8) =
                    *(const bf16x8*)&Ts[row * 40 + part * 8];
            }
        }
    }
}

// ---------------------------------------------------------------- flash attention (max-free, 32q/wave)
// Round 8: REVERT to the r4 structure (best measured: attn 75.4us, total 250.1)
// and add the only two never-isolated, low-risk edits:
//  (a) cmv register prefetch one tile ahead (cmn): r4 issued the 32 CM loads
//      ~600-1000cy before use (partially covering L3 ~600-900cy); full-tile
//      cover (~3000cy) removes the residual stall. NOTE: keeps r4's COALESCED
//      pattern (l16 on the contiguous t axis) — r7's regression came from
//      putting l16 on the row axis (16 cache lines/instr gather).
//  (b) s_setprio(1) around the QK and PV MFMA clusters (T5): 3 blocks/CU at
//      independent phases -> scheduler can favor MFMA-entering waves (+4-7%
//      on attn per learn_hip m191).
// r7's swapped-QK/global-V experiment REVERTED (dur 2.3x: uncoalesced gathers).
// Spill alarm: WRITE_SIZE > 45 MB (expect ~25 MB) -> drop (a) next round.
__global__ __launch_bounds__(256, 3) void attn_kernel(const unsigned short* __restrict__ Q,
                                                      const unsigned short* __restrict__ K,
                                                      const unsigned short* __restrict__ VT,
                                                      const float* __restrict__ CM,
                                                      const float* __restrict__ Wc,
                                                      float* __restrict__ O0,
                                                      float* __restrict__ O1,
                                                      float* __restrict__ O2,
                                                      float* __restrict__ O3,
                                                      float* __restrict__ l0,
                                                      float* __restrict__ l1,
                                                      float* __restrict__ l2,
                                                      float* __restrict__ l3,
                                                      int nsplit) {
    __shared__ unsigned short QPs[128 * LSTR];  // Q tile, then reused as P tile (wave-local rows)
    __shared__ unsigned short Ks[64 * LSTR];
    __shared__ unsigned short Vs[64 * LSTR];    // V^T tile: [d][t]
    const int tid = threadIdx.x;
    const int lane = tid & 63, wave = tid >> 6;
    const int quad = lane >> 4, l16 = lane & 15;
    const int h = blockIdx.y;
    const int q0 = blockIdx.x * 128;
    const int split = blockIdx.z;
    float* __restrict__ Op = (split == 0) ? O0 : (split == 1) ? O1 : (split == 2) ? O2 : O3;
    float* __restrict__ lp = (split == 0) ? l0 : (split == 1) ? l1 : (split == 2) ? l2 : l3;
    const float wch = Wc[h] * 0.125f * 1.44269504f;

    // t-range: distribute 64 tiles of 64 across nsplit splits (first r get +1)
    const int qt = 64 / nsplit, rt = 64 % nsplit;
    const int tb_tiles = split * qt + (split < rt ? split : rt);
    const int ntiles = qt + (split < rt ? 1 : 0);
    const int tbeg = tb_tiles * 64;
    const int tend = tbeg + ntiles * 64;

    // stage Q tile (128 rows x 8 parts = 1024 tasks), scaled
    for (int i = 0; i < 4; ++i) {
        int c = tid + 256 * i;
        int row = c >> 3, part = c & 7;
        bf16x8 v = *(const bf16x8*)(Q + ((size_t)h * SEQ + q0 + row) * HD + part * 8);
        for (int j = 0; j < 8; ++j) v[j] = (__bf16)((float)v[j] * wch);
        *(bf16x8*)&QPs[row * LSTR + part * 8] = v;
    }

    const int srow0 = tid >> 3, spart = tid & 7;
    const int srow1 = (tid + 256) >> 3;
    const unsigned short* kp0 = K + ((size_t)h * SEQ + tbeg + srow0) * HD + spart * 8;
    const unsigned short* kp1 = K + ((size_t)h * SEQ + tbeg + srow1) * HD + spart * 8;
    const unsigned short* vp0 = VT + ((size_t)h * HD + srow0) * SEQ + tbeg + spart * 8;
    const unsigned short* vp1 = VT + ((size_t)h * HD + srow1) * SEQ + tbeg + spart * 8;
    bf16x8 kr0 = *(const bf16x8*)kp0;
    bf16x8 kr1 = *(const bf16x8*)kp1;
    bf16x8 vr0 = *(const bf16x8*)vp0;
    bf16x8 vr1 = *(const bf16x8*)vp1;

    __syncthreads();  // Q staged
    // hoist Q fragments: 2 q-blocks x 2 k-halves (read once; QPs rows reused for P)
    bf16x8 a[2][2];
    for (int mi = 0; mi < 2; ++mi) {
        a[mi][0] = *(const bf16x8*)&QPs[(wave * 32 + mi * 16 + l16) * LSTR + quad * 8];
        a[mi][1] = *(const bf16x8*)&QPs[(wave * 32 + mi * 16 + l16) * LSTR + 32 + quad * 8];
    }

    f32x4 O[2][4] = {};
    float l_part[2][4] = {};
    const float* cmbase0 = CM + (size_t)(q0 + wave * 32 + quad * 4) * SEQ + l16;
    const float* cmbase1 = cmbase0 + (size_t)16 * SEQ;
    const int sw = (l16 >> 2) & 3;  // P-read swizzle key: (row>>2)&3 with row = base16 + l16

    // prologue: contact-mask values for the FIRST tile (r4-coalesced pattern:
    // l16 on the contiguous t axis -> 16 consecutive floats per lane group)
    float cmv[2][4][4];
    for (int r = 0; r < 4; ++r)
        for (int nt = 0; nt < 4; ++nt) {
            cmv[0][r][nt] = cmbase0[(size_t)r * SEQ + tbeg + nt * 16];
            cmv[1][r][nt] = cmbase1[(size_t)r * SEQ + tbeg + nt * 16];
        }

    for (int t0 = tbeg; t0 < tend; t0 += 64) {
        __syncthreads();
        *(bf16x8*)&Ks[srow0 * LSTR + spart * 8] = kr0;
        *(bf16x8*)&Ks[srow1 * LSTR + spart * 8] = kr1;
        *(bf16x8*)&Vs[srow0 * LSTR + spart * 8] = vr0;
        *(bf16x8*)&Vs[srow1 * LSTR + spart * 8] = vr1;
        __syncthreads();

        // prefetch next-tile K/V and next-tile cmv (registers; full-tile cover)
        float cmn[2][4][4];
        if (t0 + 64 < tend) {
            kr0 = *(const bf16x8*)(kp0 + (size_t)(t0 + 64 - tbeg) * HD);
            kr1 = *(const bf16x8*)(kp1 + (size_t)(t0 + 64 - tbeg) * HD);
            vr0 = *(const bf16x8*)(vp0 + (t0 + 64 - tbeg));
            vr1 = *(const bf16x8*)(vp1 + (t0 + 64 - tbeg));
            for (int r = 0; r < 4; ++r)
                for (int nt = 0; nt < 4; ++nt) {
                    cmn[0][r][nt] = cmbase0[(size_t)r * SEQ + t0 + 64 + nt * 16];
                    cmn[1][r][nt] = cmbase1[(size_t)r * SEQ + t0 + 64 + nt * 16];
                }
        }

        // ---- scores: Sc[32q x 64t] per wave; K frags shared across q-blocks
        f32x4 sc[2][4];
        __builtin_amdgcn_s_setprio(1);
        for (int nt = 0; nt < 4; ++nt) {
            bf16x8 b0 = *(const bf16x8*)&Ks[(nt * 16 + l16) * LSTR + quad * 8];
            bf16x8 b1 = *(const bf16x8*)&Ks[(nt * 16 + l16) * LSTR + 32 + quad * 8];
            for (int mi = 0; mi < 2; ++mi) {
                f32x4 z = {0.f, 0.f, 0.f, 0.f};
                z = __builtin_amdgcn_mfma_f32_16x16x32_bf16(a[mi][0], b0, z, 0, 0, 0);
                z = __builtin_amdgcn_mfma_f32_16x16x32_bf16(a[mi][1], b1, z, 0, 0, 0);
                sc[mi][nt] = z;
            }
        }
        __builtin_amdgcn_s_setprio(0);

        // ---- max-free softmax: P = 2^(sc*cm'), trunc-to-bf16, lane-local l
        // store swizzled: 16B chunk index (nt*2 + l16/8) ^ quad  [(row>>2)&3 == quad]
        for (int mi = 0; mi < 2; ++mi)
            for (int r = 0; r < 4; ++r)
                for (int nt = 0; nt < 4; ++nt) {
                    float pv = fast_exp2(sc[mi][nt][r] * cmv[mi][r][nt]);
                    l_part[mi][r] += pv;
                    union { float f; uint32_t u; } pu; pu.f = pv;
                    QPs[(wave * 32 + mi * 16 + quad * 4 + r) * LSTR
                        + (((nt * 2 + (l16 >> 3)) ^ quad) << 3) + (l16 & 7)] =
                        (unsigned short)(pu.u >> 16);
                }

        // wave-internal LDS RAW on P rows (wave-local; no barrier needed)
        asm volatile("s_waitcnt lgkmcnt(0)" ::: "memory");

        // ---- PV: O[32q x 64d] += P[32q x 64t] * V[64t x 64d]; V frags shared
        bf16x8 pa[2][2];
        for (int mi = 0; mi < 2; ++mi) {
            pa[mi][0] = *(const bf16x8*)&QPs[(wave * 32 + mi * 16 + l16) * LSTR + ((quad ^ sw) << 3)];
            pa[mi][1] = *(const bf16x8*)&QPs[(wave * 32 + mi * 16 + l16) * LSTR + 32 + ((quad ^ sw) << 3)];
        }
        __builtin_amdgcn_s_setprio(1);
        for (int nt = 0; nt < 4; ++nt) {
            bf16x8 vb0 = *(const bf16x8*)&Vs[(nt * 16 + l16) * LSTR + quad * 8];
            bf16x8 vb1 = *(const bf16x8*)&Vs[(nt * 16 + l16) * LSTR + 32 + quad * 8];
            for (int mi = 0; mi < 2; ++mi) {
                f32x4 o = O[mi][nt];
                o = __builtin_amdgcn_mfma_f32_16x16x32_bf16(pa[mi][0], vb0, o, 0, 0, 0);
                o = __builtin_amdgcn_mfma_f32_16x16x32_bf16(pa[mi][1], vb1, o, 0, 0, 0);
                O[mi][nt] = o;
            }
        }
        __builtin_amdgcn_s_setprio(0);

        // rotate cmv prefetch
        if (t0 + 64 < tend)
            for (int r = 0; r < 4; ++r)
                for (int nt = 0; nt < 4; ++nt) {
                    cmv[0][r][nt] = cmn[0][r][nt];
                    cmv[1][r][nt] = cmn[1][r][nt];
                }
    }

    // epilogue: reduce l across the 16 t-lanes of each row, store partials
    for (int mi = 0; mi < 2; ++mi)
        for (int r = 0; r < 4; ++r) {
            float s = l_part[mi][r];
            for (int off = 1; off < 16; off <<= 1) s += __shfl_xor(s, off);
            l_part[mi][r] = s;
        }
    if (l16 == 0)
        for (int mi = 0; mi < 2; ++mi)
            for (int r = 0; r < 4; ++r)
                lp[(size_t)h * SEQ + q0 + wave * 32 + mi * 16 + quad * 4 + r] = l_part[mi][r];
    for (int mi = 0; mi < 2; ++mi)
        for (int nt = 0; nt < 4; ++nt)
            for (int r = 0; r < 4; ++r) {
                int sg = q0 + wave * 32 + mi * 16 + quad * 4 + r;
                Op[((size_t)h * SEQ + sg) * HD + nt * 16 + l16] = O[mi][nt][r];
            }
}

// ---------------------------------------------------------------- combine splits -> AO bf16
__global__ __launch_bounds__(256) void combine_kernel(const float* __restrict__ O0,
                                                      const float* __restrict__ O1,
                                                      const float* __restrict__ O2,
                                                      const float* __restrict__ O3,
                                                      const float* __restrict__ l0,
                                                      const float* __restrict__ l1,
                                                      const float* __restrict__ l2,
                                                      const float* __restrict__ l3,
                                                      int nsplit,
                                                      unsigned short* __restrict__ AO) {
    int idx = blockIdx.x * 256 + threadIdx.x;
    int e = idx * 4;
    int row = e >> 6;  // h*SEQ + s
    float4 a = *(const float4*)(O0 + e);
    float4 b = *(const float4*)(O1 + e);
    float x = a.x + b.x, y = a.y + b.y, z = a.z + b.z, w = a.w + b.w;
    float ls = l0[row] + l1[row];
    if (nsplit >= 3) {
        float4 c = *(const float4*)(O2 + e);
        x += c.x; y += c.y; z += c.z; w += c.w;
        ls += l2[row];
    }
    if (nsplit >= 4) {
        float4 d = *(const float4*)(O3 + e);
        x += d.x; y += d.y; z += d.z; w += d.w;
        ls += l3[row];
    }
    float linv = 1.f / ls;
    ushort4 o;
    o.x = f2bf(x * linv);
    o.y = f2bf(y * linv);
    o.z = f2bf(z * linv);
    o.w = f2bf(w * linv);
    *(ushort4*)(AO + e) = o;
}

// ---------------------------------------------------------------- output GEMM + residual (r5 form)
__global__ __launch_bounds__(256) void out_gemm(const unsigned short* __restrict__ A,
                                                const unsigned short* __restrict__ B,
                                                const float* __restrict__ bo,
                                                const float* __restrict__ emb,
                                                float* __restrict__ X) {
    __shared__ unsigned short As[64 * 32];
    __shared__ unsigned short Bs[128 * 32];
    const int tid = threadIdx.x;
    const int lane = tid & 63, wave = tid >> 6;
    const int quad = lane >> 4, l16 = lane & 15;
    const int m0 = blockIdx.x * 64;
    const int n0 = blockIdx.y * 128;

    const int srow = tid >> 2, sqq = tid & 3;

    f32x4 acc[8] = {};

    for (int k0 = 0; k0 < NODEDIM; k0 += 32) {
        __syncthreads();
        GLOAD_LDS(A + (size_t)(m0 + srow) * NODEDIM + k0 + sqq * 8, &As[srow * 32 + sqq * 8]);
        for (int i = 0; i < 2; ++i) {
            int row = srow + 64 * i;
            GLOAD_LDS(B + (size_t)(n0 + row) * NODEDIM + k0 + sqq * 8, &Bs[row * 32 + sqq * 8]);
        }
        __syncthreads();
        bf16x8 af = *(const bf16x8*)&As[(wave * 16 + l16) * 32 + quad * 8];
        for (int ni = 0; ni < 8; ++ni) {
            bf16x8 bf = *(const bf16x8*)&Bs[(ni * 16 + l16) * 32 + quad * 8];
            acc[ni] = __builtin_amdgcn_mfma_f32_16x16x32_bf16(af, bf, acc[ni], 0, 0, 0);
        }
    }

    for (int ni = 0; ni < 8; ++ni)
        for (int r = 0; r < 4; ++r) {
            int s = m0 + wave * 16 + quad * 4 + r;
            int n = n0 + ni * 16 + l16;
            float v = acc[ni][r] + bo[n] + emb[(size_t)s * INDIM + n];
            X[(size_t)s * NODEDIM + n] = v;
        }
}

// ---------------------------------------------------------------- LayerNorm
__global__ __launch_bounds__(256) void ln_kernel(const float* __restrict__ X,
                                                 const float* __restrict__ gamma,
                                                 const float* __restrict__ beta,
                                                 float* __restrict__ out) {
    const int s = blockIdx.x;
    const int n = threadIdx.x * 2;
    float2 v = *(const float2*)&X[(size_t)s * NODEDIM + n];
    float sum = v.x + v.y;
    float sq = v.x * v.x + v.y * v.y;
    for (int off = 32; off > 0; off >>= 1) {
        sum += __shfl_down(sum, off);
        sq += __shfl_down(sq, off);
    }
    __shared__ float ssum[4], ssq[4];
    const int wave = threadIdx.x >> 6, lane = threadIdx.x & 63;
    if (lane == 0) { ssum[wave] = sum; ssq[wave] = sq; }
    __syncthreads();
    float tsum = ssum[0] + ssum[1] + ssum[2] + ssum[3];
    float tsq = ssq[0] + ssq[1] + ssq[2] + ssq[3];
    float mu = tsum * (1.f / 512.f);
    float var = tsq * (1.f / 512.f) - mu * mu;
    float rstd = rsqrtf(var + 1e-5f);
    float2 g = *(const float2*)&gamma[n];
    float2 b = *(const float2*)&beta[n];
    float2 o;
    o.x = (v.x - mu) * rstd * g.x + b.x;
    o.y = (v.y - mu) * rstd * g.y + b.y;
    *(float2*)&out[(size_t)s * NODEDIM + n] = o;
}

// ---------------------------------------------------------------- launch
extern "C" void kernel_launch(void* const* d_in, const int* in_sizes, int n_in,
                              void* d_out, int out_size, void* d_ws, size_t ws_size,
                              hipStream_t stream) {
    const float* emb = (const float*)d_in[0];
    const float* cm  = (const float*)d_in[1];
    const float* Wq  = (const float*)d_in[2];
    const float* bq  = (const float*)d_in[3];
    const float* Wk  = (const float*)d_in[4];
    const float* bk  = (const float*)d_in[5];
    const float* Wv  = (const float*)d_in[6];
    const float* bv  = (const float*)d_in[7];
    const float* Wc  = (const float*)d_in[8];
    const float* Wo  = (const float*)d_in[9];
    const float* bo  = (const float*)d_in[10];
    const float* gamma = (const float*)d_in[11];
    const float* beta  = (const float*)d_in[12];
    float* out = (float*)d_out;

    unsigned short* ws = (unsigned short*)d_ws;
    unsigned short* emb_bf  = ws;                       // 8 MB (dead after qkv_gemm)
    unsigned short* wqkv_bf = emb_bf + 4194304;         // 3 MB (dead after qkv_gemm)
    unsigned short* wo_bf   = wqkv_bf + 1572864;        // 0.5 MB
    unsigned short* Qb  = wo_bf + 262144;               // [H,S,D] bf16
    unsigned short* Kb  = Qb + 2097152;                 // [H,S,D] bf16
    unsigned short* VTb = Kb + 2097152;                 // [H,D,S] bf16
    unsigned short* AOb = VTb + 2097152;                // [H,S,D] bf16
    float* X = (float*)(AOb + 2097152);                 // 8 MB f32
    // attention split partials, overlaid on dead regions:
    float* O0 = (float*)emb_bf;                         // 8 MB (after qkv_gemm done)
    float* O1 = X;                                      // 8 MB (X written later by out_gemm)
    float* O2 = X + 2097152;                            // 8 MB (beyond prior footprint)
    float* O3 = O2 + 2097152;                           // 8 MB (only used if nz=4)
    float* l0 = (float*)wqkv_bf;                        // 4 x 128 KB in dead wqkv region
    float* l1 = l0 + NH * SEQ;
    float* l2 = l1 + NH * SEQ;
    float* l3 = l2 + NH * SEQ;

    // 3-way split needs workspace through O2's end; fall back to 2-way otherwise.
    const size_t NEED3 = 45613056ull;
    const int nz = (ws_size >= NEED3) ? 3 : 2;

    cvt_all<<<5888, 256, 0, stream>>>(emb, Wq, Wk, Wv, Wo, emb_bf, wqkv_bf, wo_bf);

    qkv_gemm<<<dim3(32, 12), 256, 0, stream>>>(emb_bf, wqkv_bf, bq, bk, bv, Qb, Kb, VTb);
    attn_kernel<<<dim3(32, 8, nz), 256, 0, stream>>>(Qb, Kb, VTb, cm, Wc,
                                                     O0, O1, O2, O3, l0, l1, l2, l3, nz);
    combine_kernel<<<2048, 256, 0, stream>>>(O0, O1, O2, O3, l0, l1, l2, l3, nz, AOb);
    out_gemm<<<dim3(64, 4), 256, 0, stream>>>(AOb, wo_bf, bo, emb, X);
    ln_kernel<<<4096, 256, 0, stream>>>(X, gamma, beta, out);
}

// Round 9
// 246.662 us; speedup vs baseline: 1.6321x; 1.6321x over previous
//
#include <hip/hip_runtime.h>
#include <stdint.h>

#define SEQ 4096
#define INDIM 1024
#define NODEDIM 512
#define NH 8
#define HD 64
#define LSTR 72  // padded LDS row stride (ushorts): 144B -> 4-bank rotation per row

typedef __bf16 bf16x8 __attribute__((ext_vector_type(8)));
typedef float f32x4 __attribute__((ext_vector_type(4)));

#define GLOAD_LDS(gp, lp) \
    __builtin_amdgcn_global_load_lds( \
        (const __attribute__((address_space(1))) void*)(gp), \
        (__attribute__((address_space(3))) void*)(lp), 16, 0, 0)

__device__ __forceinline__ unsigned short f2bf(float f) {
    union { float f; uint32_t u; } v; v.f = f;
    uint32_t u = v.u;
    uint32_t r = (u + 0x7fffu + ((u >> 16) & 1u)) >> 16;  // RNE
    return (unsigned short)r;
}

__device__ __forceinline__ float fast_exp2(float x) {
    float r;
    asm volatile("v_exp_f32 %0, %1" : "=v"(r) : "v"(x));
    return r;
}

// ---------------------------------------------------------------- cvt fp32->bf16 (all tensors, one launch)
__global__ __launch_bounds__(256) void cvt_all(const float* __restrict__ emb,
                                               const float* __restrict__ Wq,
                                               const float* __restrict__ Wk,
                                               const float* __restrict__ Wv,
                                               const float* __restrict__ Wo,
                                               unsigned short* __restrict__ demb,
                                               unsigned short* __restrict__ dwqkv,
                                               unsigned short* __restrict__ dwo) {
    int b = blockIdx.x;
    const float* src;
    unsigned short* dst;
    int off;
    if (b < 4096)      { src = emb; dst = demb;            off = b; }
    else if (b < 4608) { src = Wq;  dst = dwqkv;           off = b - 4096; }
    else if (b < 5120) { src = Wk;  dst = dwqkv + 524288;  off = b - 4608; }
    else if (b < 5632) { src = Wv;  dst = dwqkv + 1048576; off = b - 5120; }
    else               { src = Wo;  dst = dwo;             off = b - 5632; }
    int i = (off * 256 + threadIdx.x) * 4;
    float4 v = *(const float4*)(src + i);
    ushort4 o;
    o.x = f2bf(v.x); o.y = f2bf(v.y); o.z = f2bf(v.z); o.w = f2bf(v.w);
    *(ushort4*)(dst + i) = o;
}

// ---------------------------------------------------------------- QKV GEMM (r5 form)
__global__ __launch_bounds__(256) void qkv_gemm(const unsigned short* __restrict__ A,
                                                const unsigned short* __restrict__ B,
                                                const float* __restrict__ bq,
                                                const float* __restrict__ bk,
                                                const float* __restrict__ bv,
                                                unsigned short* __restrict__ Qo,
                                                unsigned short* __restrict__ Ko,
                                                unsigned short* __restrict__ VTo) {
    __shared__ unsigned short As[128 * 32];
    __shared__ unsigned short Bs[128 * 32];
    __shared__ unsigned short Ts[128 * 40];  // V-transpose staging
    const int tid = threadIdx.x;
    const int lane = tid & 63, wave = tid >> 6;
    const int wm = wave >> 1, wn = wave & 1;
    const int quad = lane >> 4, l16 = lane & 15;
    const int m0 = blockIdx.x * 128;
    const int n0 = blockIdx.y * 128;

    const int srow = tid >> 2, sqq = tid & 3;

    f32x4 acc[4][4] = {};

    for (int k0 = 0; k0 < INDIM; k0 += 32) {
        __syncthreads();
        for (int i = 0; i < 2; ++i) {
            int row = srow + 64 * i;
            GLOAD_LDS(A + (size_t)(m0 + row) * INDIM + k0 + sqq * 8, &As[row * 32 + sqq * 8]);
            GLOAD_LDS(B + (size_t)(n0 + row) * INDIM + k0 + sqq * 8, &Bs[row * 32 + sqq * 8]);
        }
        __syncthreads();
        bf16x8 af[4], bf[4];
        for (int mi = 0; mi < 4; ++mi)
            af[mi] = *(const bf16x8*)&As[(wm * 64 + mi * 16 + l16) * 32 + quad * 8];
        for (int ni = 0; ni < 4; ++ni)
            bf[ni] = *(const bf16x8*)&Bs[(wn * 64 + ni * 16 + l16) * 32 + quad * 8];
        for (int mi = 0; mi < 4; ++mi)
            for (int ni = 0; ni < 4; ++ni)
                acc[mi][ni] = __builtin_amdgcn_mfma_f32_16x16x32_bf16(af[mi], bf[ni], acc[mi][ni], 0, 0, 0);
    }

    if (blockIdx.y < 8) {
        unsigned short* outp = (blockIdx.y < 4) ? Qo : Ko;
        const float* biasp = (blockIdx.y < 4) ? bq : bk;
        for (int mi = 0; mi < 4; ++mi)
            for (int ni = 0; ni < 4; ++ni)
                for (int r = 0; r < 4; ++r) {
                    int s = m0 + wm * 64 + mi * 16 + quad * 4 + r;
                    int n = n0 + wn * 64 + ni * 16 + l16;
                    int h = (n >> 6) & 7;
                    int dd = n & 63;
                    float v = acc[mi][ni][r] + biasp[n & 511];
                    outp[((size_t)h * SEQ + s) * HD + dd] = f2bf(v);
                }
    } else {
        for (int chunk = 0; chunk < 4; ++chunk) {
            const int cwm = chunk >> 1;
            const int milo = (chunk & 1) * 2;
            __syncthreads();
            if (wm == cwm) {
                for (int mi2 = 0; mi2 < 2; ++mi2) {
                    int mi = milo + mi2;
                    for (int ni = 0; ni < 4; ++ni) {
                        int ddf = wn * 64 + ni * 16 + l16;
                        float bias = bv[(n0 + ddf) & 511];
                        for (int r = 0; r < 4; ++r) {
                            int sl = mi2 * 16 + quad * 4 + r;
                            Ts[ddf * 40 + sl] = f2bf(acc[mi][ni][r] + bias);
                        }
                    }
                }
            }
            __syncthreads();
            for (int pass = 0; pass < 2; ++pass) {
                int c = pass * 256 + tid;
                int row = c >> 2, part = c & 3;
                int nfull = n0 + row;
                int h = (nfull >> 6) & 7, dd = nfull & 63;
                *(bf16x8*)(VTo + ((size_t)h * HD + dd) * SEQ + m0 + chunk * 32 + part * 8) =
                    *(const bf16x8*)&Ts[row * 40 + part * 8];
            }
        }
    }
}

// ---------------------------------------------------------------- flash attention (max-free, 32q/wave)
// Round 9: EXACT r4 structure (best measured: attn 75.4us, total 250.08) plus
// ONLY s_setprio(1) around the two MFMA clusters (T5; zero register cost).
//   r8's cmv-prefetch spilled (3rd spill: the r4 live set is AT the (256,3)=170
//   ceiling; +32 regs -> 388 MB scratch, 227us). Prefetch is dead in this
//   structure. setprio was bundled with it in r8, never isolated; r4 runs
//   3 independent blocks/CU at different phases = m191's regime (+4-7% attn).
//   Everything else byte-identical to r4.
// Alarm: WRITE_SIZE must stay ~25 MB and VGPR ~84; any change = perturbation.
__global__ __launch_bounds__(256, 3) void attn_kernel(const unsigned short* __restrict__ Q,
                                                      const unsigned short* __restrict__ K,
                                                      const unsigned short* __restrict__ VT,
                                                      const float* __restrict__ CM,
                                                      const float* __restrict__ Wc,
                                                      float* __restrict__ O0,
                                                      float* __restrict__ O1,
                                                      float* __restrict__ O2,
                                                      float* __restrict__ O3,
                                                      float* __restrict__ l0,
                                                      float* __restrict__ l1,
                                                      float* __restrict__ l2,
                                                      float* __restrict__ l3,
                                                      int nsplit) {
    __shared__ unsigned short QPs[128 * LSTR];  // Q tile, then reused as P tile (wave-local rows)
    __shared__ unsigned short Ks[64 * LSTR];
    __shared__ unsigned short Vs[64 * LSTR];    // V^T tile: [d][t]
    const int tid = threadIdx.x;
    const int lane = tid & 63, wave = tid >> 6;
    const int quad = lane >> 4, l16 = lane & 15;
    const int h = blockIdx.y;
    const int q0 = blockIdx.x * 128;
    const int split = blockIdx.z;
    float* __restrict__ Op = (split == 0) ? O0 : (split == 1) ? O1 : (split == 2) ? O2 : O3;
    float* __restrict__ lp = (split == 0) ? l0 : (split == 1) ? l1 : (split == 2) ? l2 : l3;
    const float wch = Wc[h] * 0.125f * 1.44269504f;

    // t-range: distribute 64 tiles of 64 across nsplit splits (first r get +1)
    const int qt = 64 / nsplit, rt = 64 % nsplit;
    const int tb_tiles = split * qt + (split < rt ? split : rt);
    const int ntiles = qt + (split < rt ? 1 : 0);
    const int tbeg = tb_tiles * 64;
    const int tend = tbeg + ntiles * 64;

    // stage Q tile (128 rows x 8 parts = 1024 tasks), scaled
    for (int i = 0; i < 4; ++i) {
        int c = tid + 256 * i;
        int row = c >> 3, part = c & 7;
        bf16x8 v = *(const bf16x8*)(Q + ((size_t)h * SEQ + q0 + row) * HD + part * 8);
        for (int j = 0; j < 8; ++j) v[j] = (__bf16)((float)v[j] * wch);
        *(bf16x8*)&QPs[row * LSTR + part * 8] = v;
    }

    const int srow0 = tid >> 3, spart = tid & 7;
    const int srow1 = (tid + 256) >> 3;
    const unsigned short* kp0 = K + ((size_t)h * SEQ + tbeg + srow0) * HD + spart * 8;
    const unsigned short* kp1 = K + ((size_t)h * SEQ + tbeg + srow1) * HD + spart * 8;
    const unsigned short* vp0 = VT + ((size_t)h * HD + srow0) * SEQ + tbeg + spart * 8;
    const unsigned short* vp1 = VT + ((size_t)h * HD + srow1) * SEQ + tbeg + spart * 8;
    bf16x8 kr0 = *(const bf16x8*)kp0;
    bf16x8 kr1 = *(const bf16x8*)kp1;
    bf16x8 vr0 = *(const bf16x8*)vp0;
    bf16x8 vr1 = *(const bf16x8*)vp1;

    __syncthreads();  // Q staged
    // hoist Q fragments: 2 q-blocks x 2 k-halves (read once; QPs rows reused for P)
    bf16x8 a[2][2];
    for (int mi = 0; mi < 2; ++mi) {
        a[mi][0] = *(const bf16x8*)&QPs[(wave * 32 + mi * 16 + l16) * LSTR + quad * 8];
        a[mi][1] = *(const bf16x8*)&QPs[(wave * 32 + mi * 16 + l16) * LSTR + 32 + quad * 8];
    }

    f32x4 O[2][4] = {};
    float l_part[2][4] = {};
    const float* cmbase0 = CM + (size_t)(q0 + wave * 32 + quad * 4) * SEQ + l16;
    const float* cmbase1 = cmbase0 + (size_t)16 * SEQ;
    const int sw = (l16 >> 2) & 3;  // P-read swizzle key: (row>>2)&3 with row = base16 + l16

    for (int t0 = tbeg; t0 < tend; t0 += 64) {
        // contact-mask values for THIS tile (2 q-blocks x 4 r x 4 nt)
        float cmv[2][4][4];
        for (int r = 0; r < 4; ++r)
            for (int nt = 0; nt < 4; ++nt) {
                cmv[0][r][nt] = cmbase0[(size_t)r * SEQ + t0 + nt * 16];
                cmv[1][r][nt] = cmbase1[(size_t)r * SEQ + t0 + nt * 16];
            }

        __syncthreads();
        *(bf16x8*)&Ks[srow0 * LSTR + spart * 8] = kr0;
        *(bf16x8*)&Ks[srow1 * LSTR + spart * 8] = kr1;
        *(bf16x8*)&Vs[srow0 * LSTR + spart * 8] = vr0;
        *(bf16x8*)&Vs[srow1 * LSTR + spart * 8] = vr1;
        __syncthreads();

        if (t0 + 64 < tend) {
            kr0 = *(const bf16x8*)(kp0 + (size_t)(t0 + 64 - tbeg) * HD);
            kr1 = *(const bf16x8*)(kp1 + (size_t)(t0 + 64 - tbeg) * HD);
            vr0 = *(const bf16x8*)(vp0 + (t0 + 64 - tbeg));
            vr1 = *(const bf16x8*)(vp1 + (t0 + 64 - tbeg));
        }

        // ---- scores: Sc[32q x 64t] per wave; K frags shared across q-blocks
        f32x4 sc[2][4];
        __builtin_amdgcn_s_setprio(1);
        for (int nt = 0; nt < 4; ++nt) {
            bf16x8 b0 = *(const bf16x8*)&Ks[(nt * 16 + l16) * LSTR + quad * 8];
            bf16x8 b1 = *(const bf16x8*)&Ks[(nt * 16 + l16) * LSTR + 32 + quad * 8];
            for (int mi = 0; mi < 2; ++mi) {
                f32x4 z = {0.f, 0.f, 0.f, 0.f};
                z = __builtin_amdgcn_mfma_f32_16x16x32_bf16(a[mi][0], b0, z, 0, 0, 0);
                z = __builtin_amdgcn_mfma_f32_16x16x32_bf16(a[mi][1], b1, z, 0, 0, 0);
                sc[mi][nt] = z;
            }
        }
        __builtin_amdgcn_s_setprio(0);

        // ---- max-free softmax: P = 2^(sc*cm'), trunc-to-bf16, lane-local l
        // store swizzled: 16B chunk index (nt*2 + l16/8) ^ quad  [(row>>2)&3 == quad]
        for (int mi = 0; mi < 2; ++mi)
            for (int r = 0; r < 4; ++r)
                for (int nt = 0; nt < 4; ++nt) {
                    float pv = fast_exp2(sc[mi][nt][r] * cmv[mi][r][nt]);
                    l_part[mi][r] += pv;
                    union { float f; uint32_t u; } pu; pu.f = pv;
                    QPs[(wave * 32 + mi * 16 + quad * 4 + r) * LSTR
                        + (((nt * 2 + (l16 >> 3)) ^ quad) << 3) + (l16 & 7)] =
                        (unsigned short)(pu.u >> 16);
                }

        // wave-internal LDS RAW on P rows (wave-local; no barrier needed)
        asm volatile("s_waitcnt lgkmcnt(0)" ::: "memory");

        // ---- PV: O[32q x 64d] += P[32q x 64t] * V[64t x 64d]; V frags shared
        bf16x8 pa[2][2];
        for (int mi = 0; mi < 2; ++mi) {
            pa[mi][0] = *(const bf16x8*)&QPs[(wave * 32 + mi * 16 + l16) * LSTR + ((quad ^ sw) << 3)];
            pa[mi][1] = *(const bf16x8*)&QPs[(wave * 32 + mi * 16 + l16) * LSTR + 32 + ((quad ^ sw) << 3)];
        }
        __builtin_amdgcn_s_setprio(1);
        for (int nt = 0; nt < 4; ++nt) {
            bf16x8 vb0 = *(const bf16x8*)&Vs[(nt * 16 + l16) * LSTR + quad * 8];
            bf16x8 vb1 = *(const bf16x8*)&Vs[(nt * 16 + l16) * LSTR + 32 + quad * 8];
            for (int mi = 0; mi < 2; ++mi) {
                f32x4 o = O[mi][nt];
                o = __builtin_amdgcn_mfma_f32_16x16x32_bf16(pa[mi][0], vb0, o, 0, 0, 0);
                o = __builtin_amdgcn_mfma_f32_16x16x32_bf16(pa[mi][1], vb1, o, 0, 0, 0);
                O[mi][nt] = o;
            }
        }
        __builtin_amdgcn_s_setprio(0);
    }

    // epilogue: reduce l across the 16 t-lanes of each row, store partials
    for (int mi = 0; mi < 2; ++mi)
        for (int r = 0; r < 4; ++r) {
            float s = l_part[mi][r];
            for (int off = 1; off < 16; off <<= 1) s += __shfl_xor(s, off);
            l_part[mi][r] = s;
        }
    if (l16 == 0)
        for (int mi = 0; mi < 2; ++mi)
            for (int r = 0; r < 4; ++r)
                lp[(size_t)h * SEQ + q0 + wave * 32 + mi * 16 + quad * 4 + r] = l_part[mi][r];
    for (int mi = 0; mi < 2; ++mi)
        for (int nt = 0; nt < 4; ++nt)
            for (int r = 0; r < 4; ++r) {
                int sg = q0 + wave * 32 + mi * 16 + quad * 4 + r;
                Op[((size_t)h * SEQ + sg) * HD + nt * 16 + l16] = O[mi][nt][r];
            }
}

// ---------------------------------------------------------------- combine splits -> AO bf16
__global__ __launch_bounds__(256) void combine_kernel(const float* __restrict__ O0,
                                                      const float* __restrict__ O1,
                                                      const float* __restrict__ O2,
                                                      const float* __restrict__ O3,
                                                      const float* __restrict__ l0,
                                                      const float* __restrict__ l1,
                                                      const float* __restrict__ l2,
                                                      const float* __restrict__ l3,
                                                      int nsplit,
                                                      unsigned short* __restrict__ AO) {
    int idx = blockIdx.x * 256 + threadIdx.x;
    int e = idx * 4;
    int row = e >> 6;  // h*SEQ + s
    float4 a = *(const float4*)(O0 + e);
    float4 b = *(const float4*)(O1 + e);
    float x = a.x + b.x, y = a.y + b.y, z = a.z + b.z, w = a.w + b.w;
    float ls = l0[row] + l1[row];
    if (nsplit >= 3) {
        float4 c = *(const float4*)(O2 + e);
        x += c.x; y += c.y; z += c.z; w += c.w;
        ls += l2[row];
    }
    if (nsplit >= 4) {
        float4 d = *(const float4*)(O3 + e);
        x += d.x; y += d.y; z += d.z; w += d.w;
        ls += l3[row];
    }
    float linv = 1.f / ls;
    ushort4 o;
    o.x = f2bf(x * linv);
    o.y = f2bf(y * linv);
    o.z = f2bf(z * linv);
    o.w = f2bf(w * linv);
    *(ushort4*)(AO + e) = o;
}

// ---------------------------------------------------------------- output GEMM + residual (r5 form)
__global__ __launch_bounds__(256) void out_gemm(const unsigned short* __restrict__ A,
                                                const unsigned short* __restrict__ B,
                                                const float* __restrict__ bo,
                                                const float* __restrict__ emb,
                                                float* __restrict__ X) {
    __shared__ unsigned short As[64 * 32];
    __shared__ unsigned short Bs[128 * 32];
    const int tid = threadIdx.x;
    const int lane = tid & 63, wave = tid >> 6;
    const int quad = lane >> 4, l16 = lane & 15;
    const int m0 = blockIdx.x * 64;
    const int n0 = blockIdx.y * 128;

    const int srow = tid >> 2, sqq = tid & 3;

    f32x4 acc[8] = {};

    for (int k0 = 0; k0 < NODEDIM; k0 += 32) {
        __syncthreads();
        GLOAD_LDS(A + (size_t)(m0 + srow) * NODEDIM + k0 + sqq * 8, &As[srow * 32 + sqq * 8]);
        for (int i = 0; i < 2; ++i) {
            int row = srow + 64 * i;
            GLOAD_LDS(B + (size_t)(n0 + row) * NODEDIM + k0 + sqq * 8, &Bs[row * 32 + sqq * 8]);
        }
        __syncthreads();
        bf16x8 af = *(const bf16x8*)&As[(wave * 16 + l16) * 32 + quad * 8];
        for (int ni = 0; ni < 8; ++ni) {
            bf16x8 bf = *(const bf16x8*)&Bs[(ni * 16 + l16) * 32 + quad * 8];
            acc[ni] = __builtin_amdgcn_mfma_f32_16x16x32_bf16(af, bf, acc[ni], 0, 0, 0);
        }
    }

    for (int ni = 0; ni < 8; ++ni)
        for (int r = 0; r < 4; ++r) {
            int s = m0 + wave * 16 + quad * 4 + r;
            int n = n0 + ni * 16 + l16;
            float v = acc[ni][r] + bo[n] + emb[(size_t)s * INDIM + n];
            X[(size_t)s * NODEDIM + n] = v;
        }
}

// ---------------------------------------------------------------- LayerNorm
__global__ __launch_bounds__(256) void ln_kernel(const float* __restrict__ X,
                                                 const float* __restrict__ gamma,
                                                 const float* __restrict__ beta,
                                                 float* __restrict__ out) {
    const int s = blockIdx.x;
    const int n = threadIdx.x * 2;
    float2 v = *(const float2*)&X[(size_t)s * NODEDIM + n];
    float sum = v.x + v.y;
    float sq = v.x * v.x + v.y * v.y;
    for (int off = 32; off > 0; off >>= 1) {
        sum += __shfl_down(sum, off);
        sq += __shfl_down(sq, off);
    }
    __shared__ float ssum[4], ssq[4];
    const int wave = threadIdx.x >> 6, lane = threadIdx.x & 63;
    if (lane == 0) { ssum[wave] = sum; ssq[wave] = sq; }
    __syncthreads();
    float tsum = ssum[0] + ssum[1] + ssum[2] + ssum[3];
    float tsq = ssq[0] + ssq[1] + ssq[2] + ssq[3];
    float mu = tsum * (1.f / 512.f);
    float var = tsq * (1.f / 512.f) - mu * mu;
    float rstd = rsqrtf(var + 1e-5f);
    float2 g = *(const float2*)&gamma[n];
    float2 b = *(const float2*)&beta[n];
    float2 o;
    o.x = (v.x - mu) * rstd * g.x + b.x;
    o.y = (v.y - mu) * rstd * g.y + b.y;
    *(float2*)&out[(size_t)s * NODEDIM + n] = o;
}

// ---------------------------------------------------------------- launch
extern "C" void kernel_launch(void* const* d_in, const int* in_sizes, int n_in,
                              void* d_out, int out_size, void* d_ws, size_t ws_size,
                              hipStream_t stream) {
    const float* emb = (const float*)d_in[0];
    const float* cm  = (const float*)d_in[1];
    const float* Wq  = (const float*)d_in[2];
    const float* bq  = (const float*)d_in[3];
    const float* Wk  = (const float*)d_in[4];
    const float* bk  = (const float*)d_in[5];
    const float* Wv  = (const float*)d_in[6];
    const float* bv  = (const float*)d_in[7];
    const float* Wc  = (const float*)d_in[8];
    const float* Wo  = (const float*)d_in[9];
    const float* bo  = (const float*)d_in[10];
    const float* gamma = (const float*)d_in[11];
    const float* beta  = (const float*)d_in[12];
    float* out = (float*)d_out;

    unsigned short* ws = (unsigned short*)d_ws;
    unsigned short* emb_bf  = ws;                       // 8 MB (dead after qkv_gemm)
    unsigned short* wqkv_bf = emb_bf + 4194304;         // 3 MB (dead after qkv_gemm)
    unsigned short* wo_bf   = wqkv_bf + 1572864;        // 0.5 MB
    unsigned short* Qb  = wo_bf + 262144;               // [H,S,D] bf16
    unsigned short* Kb  = Qb + 2097152;                 // [H,S,D] bf16
    unsigned short* VTb = Kb + 2097152;                 // [H,D,S] bf16
    unsigned short* AOb = VTb + 2097152;                // [H,S,D] bf16
    float* X = (float*)(AOb + 2097152);                 // 8 MB f32
    // attention split partials, overlaid on dead regions:
    float* O0 = (float*)emb_bf;                         // 8 MB (after qkv_gemm done)
    float* O1 = X;                                      // 8 MB (X written later by out_gemm)
    float* O2 = X + 2097152;                            // 8 MB (beyond prior footprint)
    float* O3 = O2 + 2097152;                           // 8 MB (only used if nz=4)
    float* l0 = (float*)wqkv_bf;                        // 4 x 128 KB in dead wqkv region
    float* l1 = l0 + NH * SEQ;
    float* l2 = l1 + NH * SEQ;
    float* l3 = l2 + NH * SEQ;

    // 3-way split needs workspace through O2's end; fall back to 2-way otherwise.
    const size_t NEED3 = 45613056ull;
    const int nz = (ws_size >= NEED3) ? 3 : 2;

    cvt_all<<<5888, 256, 0, stream>>>(emb, Wq, Wk, Wv, Wo, emb_bf, wqkv_bf, wo_bf);

    qkv_gemm<<<dim3(32, 12), 256, 0, stream>>>(emb_bf, wqkv_bf, bq, bk, bv, Qb, Kb, VTb);
    attn_kernel<<<dim3(32, 8, nz), 256, 0, stream>>>(Qb, Kb, VTb, cm, Wc,
                                                     O0, O1, O2, O3, l0, l1, l2, l3, nz);
    combine_kernel<<<2048, 256, 0, stream>>>(O0, O1, O2, O3, l0, l1, l2, l3, nz, AOb);
    out_gemm<<<dim3(64, 4), 256, 0, stream>>>(AOb, wo_bf, bo, emb, X);
    ln_kernel<<<4096, 256, 0, stream>>>(X, gamma, beta, out);
}

// Round 10
// 232.657 us; speedup vs baseline: 1.7304x; 1.0602x over previous
//
#include <hip/hip_runtime.h>
#include <stdint.h>

#define SEQ 4096
#define INDIM 1024
#define NODEDIM 512
#define NH 8
#define HD 64
#define LSTR 72  // padded LDS row stride (ushorts): 144B -> 4-bank rotation per row

typedef __bf16 bf16x8 __attribute__((ext_vector_type(8)));
typedef float f32x4 __attribute__((ext_vector_type(4)));

#define GLOAD_LDS(gp, lp) \
    __builtin_amdgcn_global_load_lds( \
        (const __attribute__((address_space(1))) void*)(gp), \
        (__attribute__((address_space(3))) void*)(lp), 16, 0, 0)

__device__ __forceinline__ unsigned short f2bf(float f) {
    union { float f; uint32_t u; } v; v.f = f;
    uint32_t u = v.u;
    uint32_t r = (u + 0x7fffu + ((u >> 16) & 1u)) >> 16;  // RNE
    return (unsigned short)r;
}

__device__ __forceinline__ float fast_exp2(float x) {
    float r;
    asm volatile("v_exp_f32 %0, %1" : "=v"(r) : "v"(x));
    return r;
}

// ---------------------------------------------------------------- cvt fp32->bf16 (all tensors, one launch)
__global__ __launch_bounds__(256) void cvt_all(const float* __restrict__ emb,
                                               const float* __restrict__ Wq,
                                               const float* __restrict__ Wk,
                                               const float* __restrict__ Wv,
                                               const float* __restrict__ Wo,
                                               unsigned short* __restrict__ demb,
                                               unsigned short* __restrict__ dwqkv,
                                               unsigned short* __restrict__ dwo) {
    int b = blockIdx.x;
    const float* src;
    unsigned short* dst;
    int off;
    if (b < 4096)      { src = emb; dst = demb;            off = b; }
    else if (b < 4608) { src = Wq;  dst = dwqkv;           off = b - 4096; }
    else if (b < 5120) { src = Wk;  dst = dwqkv + 524288;  off = b - 4608; }
    else if (b < 5632) { src = Wv;  dst = dwqkv + 1048576; off = b - 5120; }
    else               { src = Wo;  dst = dwo;             off = b - 5632; }
    int i = (off * 256 + threadIdx.x) * 4;
    float4 v = *(const float4*)(src + i);
    ushort4 o;
    o.x = f2bf(v.x); o.y = f2bf(v.y); o.z = f2bf(v.z); o.w = f2bf(v.w);
    *(ushort4*)(dst + i) = o;
}

// ---------------------------------------------------------------- QKV GEMM
// Round 10: BM 128->64. Grid (32,12)=384 blocks was 1.5 blocks/CU — the
// barrier-drain per k-step had nothing to overlap on half the CUs (m114:
// implicit wave-level overlap needs ~3 blocks/CU). Now (64,12)=768 = exactly
// 3/CU. All proven layouts kept: BK=32, 64B LDS row stride (2-offset banking),
// global_load_lds contiguity (A: addr=tid*16B), V-transpose path now 2 chunks
// of 32 s-rows with chunk==wm. LDS 22KB, acc[2][4]=32 regs.
__global__ __launch_bounds__(256) void qkv_gemm(const unsigned short* __restrict__ A,
                                                const unsigned short* __restrict__ B,
                                                const float* __restrict__ bq,
                                                const float* __restrict__ bk,
                                                const float* __restrict__ bv,
                                                unsigned short* __restrict__ Qo,
                                                unsigned short* __restrict__ Ko,
                                                unsigned short* __restrict__ VTo) {
    __shared__ unsigned short As[64 * 32];
    __shared__ unsigned short Bs[128 * 32];
    __shared__ unsigned short Ts[128 * 40];  // V-transpose staging
    const int tid = threadIdx.x;
    const int lane = tid & 63, wave = tid >> 6;
    const int wm = wave >> 1, wn = wave & 1;
    const int quad = lane >> 4, l16 = lane & 15;
    const int m0 = blockIdx.x * 64;
    const int n0 = blockIdx.y * 128;

    const int srow = tid >> 2, sqq = tid & 3;  // srow in [0,64)

    f32x4 acc[2][4] = {};

    for (int k0 = 0; k0 < INDIM; k0 += 32) {
        __syncthreads();
        GLOAD_LDS(A + (size_t)(m0 + srow) * INDIM + k0 + sqq * 8, &As[srow * 32 + sqq * 8]);
        for (int i = 0; i < 2; ++i) {
            int row = srow + 64 * i;
            GLOAD_LDS(B + (size_t)(n0 + row) * INDIM + k0 + sqq * 8, &Bs[row * 32 + sqq * 8]);
        }
        __syncthreads();
        bf16x8 af[2], bf[4];
        for (int mi = 0; mi < 2; ++mi)
            af[mi] = *(const bf16x8*)&As[(wm * 32 + mi * 16 + l16) * 32 + quad * 8];
        for (int ni = 0; ni < 4; ++ni)
            bf[ni] = *(const bf16x8*)&Bs[(wn * 64 + ni * 16 + l16) * 32 + quad * 8];
        for (int mi = 0; mi < 2; ++mi)
            for (int ni = 0; ni < 4; ++ni)
                acc[mi][ni] = __builtin_amdgcn_mfma_f32_16x16x32_bf16(af[mi], bf[ni], acc[mi][ni], 0, 0, 0);
    }

    if (blockIdx.y < 8) {
        unsigned short* outp = (blockIdx.y < 4) ? Qo : Ko;
        const float* biasp = (blockIdx.y < 4) ? bq : bk;
        for (int mi = 0; mi < 2; ++mi)
            for (int ni = 0; ni < 4; ++ni)
                for (int r = 0; r < 4; ++r) {
                    int s = m0 + wm * 32 + mi * 16 + quad * 4 + r;
                    int n = n0 + wn * 64 + ni * 16 + l16;
                    int h = (n >> 6) & 7;
                    int dd = n & 63;
                    float v = acc[mi][ni][r] + biasp[n & 511];
                    outp[((size_t)h * SEQ + s) * HD + dd] = f2bf(v);
                }
    } else {
        // V path: transpose 64 s-rows in 2 chunks of 32 (chunk == wm's rows)
        for (int chunk = 0; chunk < 2; ++chunk) {
            __syncthreads();
            if (wm == chunk) {
                for (int mi = 0; mi < 2; ++mi) {
                    for (int ni = 0; ni < 4; ++ni) {
                        int ddf = wn * 64 + ni * 16 + l16;
                        float bias = bv[(n0 + ddf) & 511];
                        for (int r = 0; r < 4; ++r) {
                            int sl = mi * 16 + quad * 4 + r;  // 0..31 within chunk
                            Ts[ddf * 40 + sl] = f2bf(acc[mi][ni][r] + bias);
                        }
                    }
                }
            }
            __syncthreads();
            for (int pass = 0; pass < 2; ++pass) {
                int c = pass * 256 + tid;
                int row = c >> 2, part = c & 3;  // 128 n-rows x 4 parts (8 s each)
                int nfull = n0 + row;
                int h = (nfull >> 6) & 7, dd = nfull & 63;
                *(bf16x8*)(VTo + ((size_t)h * HD + dd) * SEQ + m0 + chunk * 32 + part * 8) =
                    *(const bf16x8*)&Ts[row * 40 + part * 8];
            }
        }
    }
}

// ---------------------------------------------------------------- flash attention (max-free, 32q/wave)
// FROZEN at r9 (best measured: attn 74.4us): r4 structure + setprio(1) around
// MFMA clusters. Every other lever isolated r0-r8: occupancy (r1-r4), BW (r5),
// prefetch (r6/r8: spill — live set AT the (256,3)=170 ceiling), restructure
// (r7: uncoalesced gather). Do not touch.
__global__ __launch_bounds__(256, 3) void attn_kernel(const unsigned short* __restrict__ Q,
                                                      const unsigned short* __restrict__ K,
                                                      const unsigned short* __restrict__ VT,
                                                      const float* __restrict__ CM,
                                                      const float* __restrict__ Wc,
                                                      float* __restrict__ O0,
                                                      float* __restrict__ O1,
                                                      float* __restrict__ O2,
                                                      float* __restrict__ O3,
                                                      float* __restrict__ l0,
                                                      float* __restrict__ l1,
                                                      float* __restrict__ l2,
                                                      float* __restrict__ l3,
                                                      int nsplit) {
    __shared__ unsigned short QPs[128 * LSTR];  // Q tile, then reused as P tile (wave-local rows)
    __shared__ unsigned short Ks[64 * LSTR];
    __shared__ unsigned short Vs[64 * LSTR];    // V^T tile: [d][t]
    const int tid = threadIdx.x;
    const int lane = tid & 63, wave = tid >> 6;
    const int quad = lane >> 4, l16 = lane & 15;
    const int h = blockIdx.y;
    const int q0 = blockIdx.x * 128;
    const int split = blockIdx.z;
    float* __restrict__ Op = (split == 0) ? O0 : (split == 1) ? O1 : (split == 2) ? O2 : O3;
    float* __restrict__ lp = (split == 0) ? l0 : (split == 1) ? l1 : (split == 2) ? l2 : l3;
    const float wch = Wc[h] * 0.125f * 1.44269504f;

    // t-range: distribute 64 tiles of 64 across nsplit splits (first r get +1)
    const int qt = 64 / nsplit, rt = 64 % nsplit;
    const int tb_tiles = split * qt + (split < rt ? split : rt);
    const int ntiles = qt + (split < rt ? 1 : 0);
    const int tbeg = tb_tiles * 64;
    const int tend = tbeg + ntiles * 64;

    // stage Q tile (128 rows x 8 parts = 1024 tasks), scaled
    for (int i = 0; i < 4; ++i) {
        int c = tid + 256 * i;
        int row = c >> 3, part = c & 7;
        bf16x8 v = *(const bf16x8*)(Q + ((size_t)h * SEQ + q0 + row) * HD + part * 8);
        for (int j = 0; j < 8; ++j) v[j] = (__bf16)((float)v[j] * wch);
        *(bf16x8*)&QPs[row * LSTR + part * 8] = v;
    }

    const int srow0 = tid >> 3, spart = tid & 7;
    const int srow1 = (tid + 256) >> 3;
    const unsigned short* kp0 = K + ((size_t)h * SEQ + tbeg + srow0) * HD + spart * 8;
    const unsigned short* kp1 = K + ((size_t)h * SEQ + tbeg + srow1) * HD + spart * 8;
    const unsigned short* vp0 = VT + ((size_t)h * HD + srow0) * SEQ + tbeg + spart * 8;
    const unsigned short* vp1 = VT + ((size_t)h * HD + srow1) * SEQ + tbeg + spart * 8;
    bf16x8 kr0 = *(const bf16x8*)kp0;
    bf16x8 kr1 = *(const bf16x8*)kp1;
    bf16x8 vr0 = *(const bf16x8*)vp0;
    bf16x8 vr1 = *(const bf16x8*)vp1;

    __syncthreads();  // Q staged
    // hoist Q fragments: 2 q-blocks x 2 k-halves (read once; QPs rows reused for P)
    bf16x8 a[2][2];
    for (int mi = 0; mi < 2; ++mi) {
        a[mi][0] = *(const bf16x8*)&QPs[(wave * 32 + mi * 16 + l16) * LSTR + quad * 8];
        a[mi][1] = *(const bf16x8*)&QPs[(wave * 32 + mi * 16 + l16) * LSTR + 32 + quad * 8];
    }

    f32x4 O[2][4] = {};
    float l_part[2][4] = {};
    const float* cmbase0 = CM + (size_t)(q0 + wave * 32 + quad * 4) * SEQ + l16;
    const float* cmbase1 = cmbase0 + (size_t)16 * SEQ;
    const int sw = (l16 >> 2) & 3;  // P-read swizzle key: (row>>2)&3 with row = base16 + l16

    for (int t0 = tbeg; t0 < tend; t0 += 64) {
        // contact-mask values for THIS tile (2 q-blocks x 4 r x 4 nt)
        float cmv[2][4][4];
        for (int r = 0; r < 4; ++r)
            for (int nt = 0; nt < 4; ++nt) {
                cmv[0][r][nt] = cmbase0[(size_t)r * SEQ + t0 + nt * 16];
                cmv[1][r][nt] = cmbase1[(size_t)r * SEQ + t0 + nt * 16];
            }

        __syncthreads();
        *(bf16x8*)&Ks[srow0 * LSTR + spart * 8] = kr0;
        *(bf16x8*)&Ks[srow1 * LSTR + spart * 8] = kr1;
        *(bf16x8*)&Vs[srow0 * LSTR + spart * 8] = vr0;
        *(bf16x8*)&Vs[srow1 * LSTR + spart * 8] = vr1;
        __syncthreads();

        if (t0 + 64 < tend) {
            kr0 = *(const bf16x8*)(kp0 + (size_t)(t0 + 64 - tbeg) * HD);
            kr1 = *(const bf16x8*)(kp1 + (size_t)(t0 + 64 - tbeg) * HD);
            vr0 = *(const bf16x8*)(vp0 + (t0 + 64 - tbeg));
            vr1 = *(const bf16x8*)(vp1 + (t0 + 64 - tbeg));
        }

        // ---- scores: Sc[32q x 64t] per wave; K frags shared across q-blocks
        f32x4 sc[2][4];
        __builtin_amdgcn_s_setprio(1);
        for (int nt = 0; nt < 4; ++nt) {
            bf16x8 b0 = *(const bf16x8*)&Ks[(nt * 16 + l16) * LSTR + quad * 8];
            bf16x8 b1 = *(const bf16x8*)&Ks[(nt * 16 + l16) * LSTR + 32 + quad * 8];
            for (int mi = 0; mi < 2; ++mi) {
                f32x4 z = {0.f, 0.f, 0.f, 0.f};
                z = __builtin_amdgcn_mfma_f32_16x16x32_bf16(a[mi][0], b0, z, 0, 0, 0);
                z = __builtin_amdgcn_mfma_f32_16x16x32_bf16(a[mi][1], b1, z, 0, 0, 0);
                sc[mi][nt] = z;
            }
        }
        __builtin_amdgcn_s_setprio(0);

        // ---- max-free softmax: P = 2^(sc*cm'), trunc-to-bf16, lane-local l
        // store swizzled: 16B chunk index (nt*2 + l16/8) ^ quad  [(row>>2)&3 == quad]
        for (int mi = 0; mi < 2; ++mi)
            for (int r = 0; r < 4; ++r)
                for (int nt = 0; nt < 4; ++nt) {
                    float pv = fast_exp2(sc[mi][nt][r] * cmv[mi][r][nt]);
                    l_part[mi][r] += pv;
                    union { float f; uint32_t u; } pu; pu.f = pv;
                    QPs[(wave * 32 + mi * 16 + quad * 4 + r) * LSTR
                        + (((nt * 2 + (l16 >> 3)) ^ quad) << 3) + (l16 & 7)] =
                        (unsigned short)(pu.u >> 16);
                }

        // wave-internal LDS RAW on P rows (wave-local; no barrier needed)
        asm volatile("s_waitcnt lgkmcnt(0)" ::: "memory");

        // ---- PV: O[32q x 64d] += P[32q x 64t] * V[64t x 64d]; V frags shared
        bf16x8 pa[2][2];
        for (int mi = 0; mi < 2; ++mi) {
            pa[mi][0] = *(const bf16x8*)&QPs[(wave * 32 + mi * 16 + l16) * LSTR + ((quad ^ sw) << 3)];
            pa[mi][1] = *(const bf16x8*)&QPs[(wave * 32 + mi * 16 + l16) * LSTR + 32 + ((quad ^ sw) << 3)];
        }
        __builtin_amdgcn_s_setprio(1);
        for (int nt = 0; nt < 4; ++nt) {
            bf16x8 vb0 = *(const bf16x8*)&Vs[(nt * 16 + l16) * LSTR + quad * 8];
            bf16x8 vb1 = *(const bf16x8*)&Vs[(nt * 16 + l16) * LSTR + 32 + quad * 8];
            for (int mi = 0; mi < 2; ++mi) {
                f32x4 o = O[mi][nt];
                o = __builtin_amdgcn_mfma_f32_16x16x32_bf16(pa[mi][0], vb0, o, 0, 0, 0);
                o = __builtin_amdgcn_mfma_f32_16x16x32_bf16(pa[mi][1], vb1, o, 0, 0, 0);
                O[mi][nt] = o;
            }
        }
        __builtin_amdgcn_s_setprio(0);
    }

    // epilogue: reduce l across the 16 t-lanes of each row, store partials
    for (int mi = 0; mi < 2; ++mi)
        for (int r = 0; r < 4; ++r) {
            float s = l_part[mi][r];
            for (int off = 1; off < 16; off <<= 1) s += __shfl_xor(s, off);
            l_part[mi][r] = s;
        }
    if (l16 == 0)
        for (int mi = 0; mi < 2; ++mi)
            for (int r = 0; r < 4; ++r)
                lp[(size_t)h * SEQ + q0 + wave * 32 + mi * 16 + quad * 4 + r] = l_part[mi][r];
    for (int mi = 0; mi < 2; ++mi)
        for (int nt = 0; nt < 4; ++nt)
            for (int r = 0; r < 4; ++r) {
                int sg = q0 + wave * 32 + mi * 16 + quad * 4 + r;
                Op[((size_t)h * SEQ + sg) * HD + nt * 16 + l16] = O[mi][nt][r];
            }
}

// ---------------------------------------------------------------- combine splits -> AO bf16
__global__ __launch_bounds__(256) void combine_kernel(const float* __restrict__ O0,
                                                      const float* __restrict__ O1,
                                                      const float* __restrict__ O2,
                                                      const float* __restrict__ O3,
                                                      const float* __restrict__ l0,
                                                      const float* __restrict__ l1,
                                                      const float* __restrict__ l2,
                                                      const float* __restrict__ l3,
                                                      int nsplit,
                                                      unsigned short* __restrict__ AO) {
    int idx = blockIdx.x * 256 + threadIdx.x;
    int e = idx * 4;
    int row = e >> 6;  // h*SEQ + s
    float4 a = *(const float4*)(O0 + e);
    float4 b = *(const float4*)(O1 + e);
    float x = a.x + b.x, y = a.y + b.y, z = a.z + b.z, w = a.w + b.w;
    float ls = l0[row] + l1[row];
    if (nsplit >= 3) {
        float4 c = *(const float4*)(O2 + e);
        x += c.x; y += c.y; z += c.z; w += c.w;
        ls += l2[row];
    }
    if (nsplit >= 4) {
        float4 d = *(const float4*)(O3 + e);
        x += d.x; y += d.y; z += d.z; w += d.w;
        ls += l3[row];
    }
    float linv = 1.f / ls;
    ushort4 o;
    o.x = f2bf(x * linv);
    o.y = f2bf(y * linv);
    o.z = f2bf(z * linv);
    o.w = f2bf(w * linv);
    *(ushort4*)(AO + e) = o;
}

// ---------------------------------------------------------------- output GEMM + residual
// Round 10: BM 64->32. Grid (64,4)=256 blocks was exactly 1 block/CU — zero
// inter-block overlap, all 16 k-steps latency-exposed. Now (128,4)=512 = 2/CU.
// Waves 2x2 (wr rows, wc cols); acc[4]; A-load by waves 0-1 only (whole-wave
// guard preserves global_load_lds wave-uniform-base contiguity).
__global__ __launch_bounds__(256) void out_gemm(const unsigned short* __restrict__ A,
                                                const unsigned short* __restrict__ B,
                                                const float* __restrict__ bo,
                                                const float* __restrict__ emb,
                                                float* __restrict__ X) {
    __shared__ unsigned short As[32 * 32];
    __shared__ unsigned short Bs[128 * 32];
    const int tid = threadIdx.x;
    const int lane = tid & 63, wave = tid >> 6;
    const int wr = wave >> 1, wc = wave & 1;
    const int quad = lane >> 4, l16 = lane & 15;
    const int m0 = blockIdx.x * 32;
    const int n0 = blockIdx.y * 128;

    const int srow = tid >> 2, sqq = tid & 3;

    f32x4 acc[4] = {};

    for (int k0 = 0; k0 < NODEDIM; k0 += 32) {
        __syncthreads();
        if (tid < 128)
            GLOAD_LDS(A + (size_t)(m0 + srow) * NODEDIM + k0 + sqq * 8, &As[srow * 32 + sqq * 8]);
        for (int i = 0; i < 2; ++i) {
            int row = srow + 64 * i;
            GLOAD_LDS(B + (size_t)(n0 + row) * NODEDIM + k0 + sqq * 8, &Bs[row * 32 + sqq * 8]);
        }
        __syncthreads();
        bf16x8 af = *(const bf16x8*)&As[(wr * 16 + l16) * 32 + quad * 8];
        for (int ni = 0; ni < 4; ++ni) {
            bf16x8 bf = *(const bf16x8*)&Bs[(wc * 64 + ni * 16 + l16) * 32 + quad * 8];
            acc[ni] = __builtin_amdgcn_mfma_f32_16x16x32_bf16(af, bf, acc[ni], 0, 0, 0);
        }
    }

    for (int ni = 0; ni < 4; ++ni)
        for (int r = 0; r < 4; ++r) {
            int s = m0 + wr * 16 + quad * 4 + r;
            int n = n0 + wc * 64 + ni * 16 + l16;
            float v = acc[ni][r] + bo[n] + emb[(size_t)s * INDIM + n];
            X[(size_t)s * NODEDIM + n] = v;
        }
}

// ---------------------------------------------------------------- LayerNorm
__global__ __launch_bounds__(256) void ln_kernel(const float* __restrict__ X,
                                                 const float* __restrict__ gamma,
                                                 const float* __restrict__ beta,
                                                 float* __restrict__ out) {
    const int s = blockIdx.x;
    const int n = threadIdx.x * 2;
    float2 v = *(const float2*)&X[(size_t)s * NODEDIM + n];
    float sum = v.x + v.y;
    float sq = v.x * v.x + v.y * v.y;
    for (int off = 32; off > 0; off >>= 1) {
        sum += __shfl_down(sum, off);
        sq += __shfl_down(sq, off);
    }
    __shared__ float ssum[4], ssq[4];
    const int wave = threadIdx.x >> 6, lane = threadIdx.x & 63;
    if (lane == 0) { ssum[wave] = sum; ssq[wave] = sq; }
    __syncthreads();
    float tsum = ssum[0] + ssum[1] + ssum[2] + ssum[3];
    float tsq = ssq[0] + ssq[1] + ssq[2] + ssq[3];
    float mu = tsum * (1.f / 512.f);
    float var = tsq * (1.f / 512.f) - mu * mu;
    float rstd = rsqrtf(var + 1e-5f);
    float2 g = *(const float2*)&gamma[n];
    float2 b = *(const float2*)&beta[n];
    float2 o;
    o.x = (v.x - mu) * rstd * g.x + b.x;
    o.y = (v.y - mu) * rstd * g.y + b.y;
    *(float2*)&out[(size_t)s * NODEDIM + n] = o;
}

// ---------------------------------------------------------------- launch
extern "C" void kernel_launch(void* const* d_in, const int* in_sizes, int n_in,
                              void* d_out, int out_size, void* d_ws, size_t ws_size,
                              hipStream_t stream) {
    const float* emb = (const float*)d_in[0];
    const float* cm  = (const float*)d_in[1];
    const float* Wq  = (const float*)d_in[2];
    const float* bq  = (const float*)d_in[3];
    const float* Wk  = (const float*)d_in[4];
    const float* bk  = (const float*)d_in[5];
    const float* Wv  = (const float*)d_in[6];
    const float* bv  = (const float*)d_in[7];
    const float* Wc  = (const float*)d_in[8];
    const float* Wo  = (const float*)d_in[9];
    const float* bo  = (const float*)d_in[10];
    const float* gamma = (const float*)d_in[11];
    const float* beta  = (const float*)d_in[12];
    float* out = (float*)d_out;

    unsigned short* ws = (unsigned short*)d_ws;
    unsigned short* emb_bf  = ws;                       // 8 MB (dead after qkv_gemm)
    unsigned short* wqkv_bf = emb_bf + 4194304;         // 3 MB (dead after qkv_gemm)
    unsigned short* wo_bf   = wqkv_bf + 1572864;        // 0.5 MB
    unsigned short* Qb  = wo_bf + 262144;               // [H,S,D] bf16
    unsigned short* Kb  = Qb + 2097152;                 // [H,S,D] bf16
    unsigned short* VTb = Kb + 2097152;                 // [H,D,S] bf16
    unsigned short* AOb = VTb + 2097152;                // [H,S,D] bf16
    float* X = (float*)(AOb + 2097152);                 // 8 MB f32
    // attention split partials, overlaid on dead regions:
    float* O0 = (float*)emb_bf;                         // 8 MB (after qkv_gemm done)
    float* O1 = X;                                      // 8 MB (X written later by out_gemm)
    float* O2 = X + 2097152;                            // 8 MB (beyond prior footprint)
    float* O3 = O2 + 2097152;                           // 8 MB (only used if nz=4)
    float* l0 = (float*)wqkv_bf;                        // 4 x 128 KB in dead wqkv region
    float* l1 = l0 + NH * SEQ;
    float* l2 = l1 + NH * SEQ;
    float* l3 = l2 + NH * SEQ;

    // 3-way split needs workspace through O2's end; fall back to 2-way otherwise.
    const size_t NEED3 = 45613056ull;
    const int nz = (ws_size >= NEED3) ? 3 : 2;

    cvt_all<<<5888, 256, 0, stream>>>(emb, Wq, Wk, Wv, Wo, emb_bf, wqkv_bf, wo_bf);

    qkv_gemm<<<dim3(64, 12), 256, 0, stream>>>(emb_bf, wqkv_bf, bq, bk, bv, Qb, Kb, VTb);
    attn_kernel<<<dim3(32, 8, nz), 256, 0, stream>>>(Qb, Kb, VTb, cm, Wc,
                                                     O0, O1, O2, O3, l0, l1, l2, l3, nz);
    combine_kernel<<<2048, 256, 0, stream>>>(O0, O1, O2, O3, l0, l1, l2, l3, nz, AOb);
    out_gemm<<<dim3(128, 4), 256, 0, stream>>>(AOb, wo_bf, bo, emb, X);
    ln_kernel<<<4096, 256, 0, stream>>>(X, gamma, beta, out);
}